// Round 1
// baseline (1655.266 us; speedup 1.0000x reference)
//
#include <hip/hip_runtime.h>
#include <hip/hip_bf16.h>
#include <stdint.h>

#define DM   1024
#define BATCH 4
#define SEQ  4096
#define MTOT (BATCH*SEQ)   // 16384

typedef __attribute__((ext_vector_type(8))) short bf16x8;
typedef __attribute__((ext_vector_type(4))) float f32x4;

// f32 -> bf16 bits, round-to-nearest-even
__device__ __forceinline__ ushort f2bf(float f){
  uint u = __float_as_uint(f);
  u += 0x7FFFu + ((u >> 16) & 1u);
  return (ushort)(u >> 16);
}
__device__ __forceinline__ float bf2f(ushort b){ return __uint_as_float(((uint)b) << 16); }

__device__ __forceinline__ void split4(const float4 v, ushort4& h4, ushort4& l4){
  h4.x = f2bf(v.x); l4.x = f2bf(v.x - bf2f(h4.x));
  h4.y = f2bf(v.y); l4.y = f2bf(v.y - bf2f(h4.y));
  h4.z = f2bf(v.z); l4.z = f2bf(v.z - bf2f(h4.z));
  h4.w = f2bf(v.w); l4.w = f2bf(v.w - bf2f(h4.w));
}

// ---------------------------------------------------------------------------
// prep_w: transpose w[k][n] -> wt[n][k], split into bf16 hi/lo planes.
// grid (32,32,2), block 256. z selects w1/w2.
// ---------------------------------------------------------------------------
__global__ __launch_bounds__(256)
void prep_w(const float* __restrict__ w1, const float* __restrict__ w2,
            ushort* __restrict__ wt1h, ushort* __restrict__ wt1l,
            ushort* __restrict__ wt2h, ushort* __restrict__ wt2l){
  __shared__ float s[32][33];
  const float* w = blockIdx.z ? w2 : w1;
  ushort* oh = blockIdx.z ? wt2h : wt1h;
  ushort* ol = blockIdx.z ? wt2l : wt1l;
  const int n0 = blockIdx.x * 32, k0 = blockIdx.y * 32;
  const int tx = threadIdx.x & 31, ty = threadIdx.x >> 5;
  for (int r = 0; r < 4; r++){
    s[ty + r*8][tx] = w[(size_t)(k0 + ty + r*8) * DM + n0 + tx];
  }
  __syncthreads();
  for (int r = 0; r < 4; r++){
    int n = ty + r*8;                 // local n index
    float v = s[tx][n];               // = w[k0+tx][n0+n]
    ushort h = f2bf(v);
    float lo = v - bf2f(h);
    size_t o = (size_t)(n0 + n) * DM + k0 + tx;   // wt[n][k], k coalesced
    oh[o] = h;
    ol[o] = f2bf(lo);
  }
}

// ---------------------------------------------------------------------------
// gemm_xw: h = hidden @ w1 + b1 (z=0) ; i = (hidden+pre) @ w2 + b2 (z=1)
// A: f32 global, converted to split-bf16 in staging. B: pre-split wt planes.
// Output: split-bf16 planes. Tile 128x128, BK=32, 3 MFMAs per frag pair.
// grid (DM/128=8, MTOT/128=128, 2), block 256 (4 waves, 2x2, each 64x64).
// ---------------------------------------------------------------------------
__global__ __launch_bounds__(256, 2)
void gemm_xw(const float* __restrict__ hidden, const float* __restrict__ pre,
             const ushort* __restrict__ w1h, const ushort* __restrict__ w1l,
             const ushort* __restrict__ w2h, const ushort* __restrict__ w2l,
             const float* __restrict__ b1, const float* __restrict__ b2,
             ushort* __restrict__ hh, ushort* __restrict__ hl,
             ushort* __restrict__ ih, ushort* __restrict__ il){
  const int z = blockIdx.z;
  const ushort* wh = z ? w2h : w1h;
  const ushort* wl = z ? w2l : w1l;
  const float* bias = z ? b2 : b1;
  ushort* oh = z ? ih : hh;
  ushort* ol = z ? il : hl;
  const int m0 = blockIdx.y * 128, n0 = blockIdx.x * 128;

  __shared__ alignas(16) ushort Ah[128*32];
  __shared__ alignas(16) ushort Al[128*32];
  __shared__ alignas(16) ushort Bh[128*32];
  __shared__ alignas(16) ushort Bl[128*32];

  const int tid = threadIdx.x;
  const int lane = tid & 63, wid = tid >> 6;
  const int wm = (wid & 1) * 64, wn = (wid >> 1) * 64;
  const int lr = lane & 15, lk = (lane >> 4) * 8;

  f32x4 acc[4][4];
  for (int i = 0; i < 4; i++) for (int j = 0; j < 4; j++) acc[i][j] = (f32x4){0.f,0.f,0.f,0.f};

  for (int k0 = 0; k0 < DM; k0 += 32){
    __syncthreads();
    #pragma unroll
    for (int c = 0; c < 4; c++){
      int idx = c * 256 + tid;
      int row = idx >> 3, kq = (idx & 7) * 4;
      size_t ga = (size_t)(m0 + row) * DM + k0 + kq;
      float4 v = *(const float4*)&hidden[ga];
      if (z){
        float4 p = *(const float4*)&pre[ga];
        v.x += p.x; v.y += p.y; v.z += p.z; v.w += p.w;
      }
      ushort4 h4, l4;
      split4(v, h4, l4);
      *(ushort4*)&Ah[row*32 + kq] = h4;
      *(ushort4*)&Al[row*32 + kq] = l4;
      size_t gb = (size_t)(n0 + row) * DM + k0 + kq;
      *(ushort4*)&Bh[row*32 + kq] = *(const ushort4*)&wh[gb];
      *(ushort4*)&Bl[row*32 + kq] = *(const ushort4*)&wl[gb];
    }
    __syncthreads();

    bf16x8 fah[4], fal[4], fbh[4], fbl[4];
    #pragma unroll
    for (int i = 0; i < 4; i++){
      fah[i] = *(const bf16x8*)&Ah[(wm + i*16 + lr)*32 + lk];
      fal[i] = *(const bf16x8*)&Al[(wm + i*16 + lr)*32 + lk];
      fbh[i] = *(const bf16x8*)&Bh[(wn + i*16 + lr)*32 + lk];
      fbl[i] = *(const bf16x8*)&Bl[(wn + i*16 + lr)*32 + lk];
    }
    #pragma unroll
    for (int i = 0; i < 4; i++)
      #pragma unroll
      for (int j = 0; j < 4; j++){
        acc[i][j] = __builtin_amdgcn_mfma_f32_16x16x32_bf16(fah[i], fbh[j], acc[i][j], 0, 0, 0);
        acc[i][j] = __builtin_amdgcn_mfma_f32_16x16x32_bf16(fah[i], fbl[j], acc[i][j], 0, 0, 0);
        acc[i][j] = __builtin_amdgcn_mfma_f32_16x16x32_bf16(fal[i], fbh[j], acc[i][j], 0, 0, 0);
      }
  }

  const int rbase = (lane >> 4) * 4;
  #pragma unroll
  for (int i = 0; i < 4; i++)
    #pragma unroll
    for (int j = 0; j < 4; j++){
      int gc = n0 + wn + j*16 + lr;
      float bv = bias[gc];
      #pragma unroll
      for (int r = 0; r < 4; r++){
        int gr = m0 + wm + i*16 + rbase + r;
        float v = acc[i][j][r] + bv;
        ushort hb = f2bf(v);
        size_t o = (size_t)gr * DM + gc;
        oh[o] = hb;
        ol[o] = f2bf(v - bf2f(hb));
      }
    }
}

// ---------------------------------------------------------------------------
// gemm_scores: out[b,q,k] = sum_d h[b,q,d] * i[b,k,d]   (raw logits, f32)
// A and B both split-bf16 planes. grid (32,32,4), block 256.
// ---------------------------------------------------------------------------
__global__ __launch_bounds__(256, 2)
void gemm_scores(const ushort* __restrict__ hh, const ushort* __restrict__ hl,
                 const ushort* __restrict__ ih, const ushort* __restrict__ il,
                 float* __restrict__ out){
  const int b = blockIdx.z;
  const int m0 = blockIdx.y * 128, n0 = blockIdx.x * 128;
  const size_t abase = (size_t)b * SEQ * DM;

  __shared__ alignas(16) ushort Ah[128*32];
  __shared__ alignas(16) ushort Al[128*32];
  __shared__ alignas(16) ushort Bh[128*32];
  __shared__ alignas(16) ushort Bl[128*32];

  const int tid = threadIdx.x;
  const int lane = tid & 63, wid = tid >> 6;
  const int wm = (wid & 1) * 64, wn = (wid >> 1) * 64;
  const int lr = lane & 15, lk = (lane >> 4) * 8;

  f32x4 acc[4][4];
  for (int i = 0; i < 4; i++) for (int j = 0; j < 4; j++) acc[i][j] = (f32x4){0.f,0.f,0.f,0.f};

  for (int k0 = 0; k0 < DM; k0 += 32){
    __syncthreads();
    #pragma unroll
    for (int c = 0; c < 4; c++){
      int idx = c * 256 + tid;
      int row = idx >> 3, kq = (idx & 7) * 4;
      size_t ga = abase + (size_t)(m0 + row) * DM + k0 + kq;
      size_t gb = abase + (size_t)(n0 + row) * DM + k0 + kq;
      *(ushort4*)&Ah[row*32 + kq] = *(const ushort4*)&hh[ga];
      *(ushort4*)&Al[row*32 + kq] = *(const ushort4*)&hl[ga];
      *(ushort4*)&Bh[row*32 + kq] = *(const ushort4*)&ih[gb];
      *(ushort4*)&Bl[row*32 + kq] = *(const ushort4*)&il[gb];
    }
    __syncthreads();

    bf16x8 fah[4], fal[4], fbh[4], fbl[4];
    #pragma unroll
    for (int i = 0; i < 4; i++){
      fah[i] = *(const bf16x8*)&Ah[(wm + i*16 + lr)*32 + lk];
      fal[i] = *(const bf16x8*)&Al[(wm + i*16 + lr)*32 + lk];
      fbh[i] = *(const bf16x8*)&Bh[(wn + i*16 + lr)*32 + lk];
      fbl[i] = *(const bf16x8*)&Bl[(wn + i*16 + lr)*32 + lk];
    }
    #pragma unroll
    for (int i = 0; i < 4; i++)
      #pragma unroll
      for (int j = 0; j < 4; j++){
        acc[i][j] = __builtin_amdgcn_mfma_f32_16x16x32_bf16(fah[i], fbh[j], acc[i][j], 0, 0, 0);
        acc[i][j] = __builtin_amdgcn_mfma_f32_16x16x32_bf16(fah[i], fbl[j], acc[i][j], 0, 0, 0);
        acc[i][j] = __builtin_amdgcn_mfma_f32_16x16x32_bf16(fal[i], fbh[j], acc[i][j], 0, 0, 0);
      }
  }

  const int rbase = (lane >> 4) * 4;
  #pragma unroll
  for (int i = 0; i < 4; i++)
    #pragma unroll
    for (int j = 0; j < 4; j++){
      int gc = n0 + wn + j*16 + lr;
      #pragma unroll
      for (int r = 0; r < 4; r++){
        int gr = m0 + wm + i*16 + rbase + r;
        out[((size_t)b * SEQ + gr) * SEQ + gc] = acc[i][j][r];
      }
    }
}

// ---------------------------------------------------------------------------
// softmax_rows: in-place row softmax over last dim (4096). One block per row.
// ---------------------------------------------------------------------------
__global__ __launch_bounds__(256)
void softmax_rows(float* __restrict__ out){
  __shared__ float red[256];
  const size_t row = blockIdx.x;
  float* p = out + row * (size_t)SEQ;
  const int tid = threadIdx.x;

  float4 v[4];
  float m = -3.0e38f;
  #pragma unroll
  for (int c = 0; c < 4; c++){
    v[c] = ((const float4*)p)[c*256 + tid];
    m = fmaxf(m, fmaxf(fmaxf(v[c].x, v[c].y), fmaxf(v[c].z, v[c].w)));
  }
  red[tid] = m; __syncthreads();
  for (int o = 128; o > 0; o >>= 1){
    if (tid < o) red[tid] = fmaxf(red[tid], red[tid + o]);
    __syncthreads();
  }
  const float M = red[0];
  __syncthreads();

  float s = 0.f;
  #pragma unroll
  for (int c = 0; c < 4; c++){
    v[c].x = __expf(v[c].x - M); s += v[c].x;
    v[c].y = __expf(v[c].y - M); s += v[c].y;
    v[c].z = __expf(v[c].z - M); s += v[c].z;
    v[c].w = __expf(v[c].w - M); s += v[c].w;
  }
  red[tid] = s; __syncthreads();
  for (int o = 128; o > 0; o >>= 1){
    if (tid < o) red[tid] += red[tid + o];
    __syncthreads();
  }
  const float inv = 1.0f / red[0];
  #pragma unroll
  for (int c = 0; c < 4; c++){
    v[c].x *= inv; v[c].y *= inv; v[c].z *= inv; v[c].w *= inv;
    ((float4*)p)[c*256 + tid] = v[c];
  }
}

// ---------------------------------------------------------------------------
extern "C" void kernel_launch(void* const* d_in, const int* in_sizes, int n_in,
                              void* d_out, int out_size, void* d_ws, size_t ws_size,
                              hipStream_t stream){
  const float* hidden = (const float*)d_in[0];
  const float* pre    = (const float*)d_in[1];
  const float* w1     = (const float*)d_in[2];
  const float* b1     = (const float*)d_in[3];
  const float* w2     = (const float*)d_in[4];
  const float* b2     = (const float*)d_in[5];
  float* out = (float*)d_out;

  char* ws = (char*)d_ws;
  const size_t WPLANE = (size_t)DM * DM * sizeof(ushort);     // 2 MiB
  const size_t APLANE = (size_t)MTOT * DM * sizeof(ushort);   // 32 MiB
  ushort* w1h = (ushort*)(ws + 0*WPLANE);
  ushort* w1l = (ushort*)(ws + 1*WPLANE);
  ushort* w2h = (ushort*)(ws + 2*WPLANE);
  ushort* w2l = (ushort*)(ws + 3*WPLANE);
  char* act = ws + 4*WPLANE;
  ushort* hh = (ushort*)(act + 0*APLANE);
  ushort* hl = (ushort*)(act + 1*APLANE);
  ushort* ih = (ushort*)(act + 2*APLANE);
  ushort* il = (ushort*)(act + 3*APLANE);

  prep_w<<<dim3(32, 32, 2), 256, 0, stream>>>(w1, w2, w1h, w1l, w2h, w2l);
  gemm_xw<<<dim3(DM/128, MTOT/128, 2), 256, 0, stream>>>(
      hidden, pre, w1h, w1l, w2h, w2l, b1, b2, hh, hl, ih, il);
  gemm_scores<<<dim3(SEQ/128, SEQ/128, BATCH), 256, 0, stream>>>(hh, hl, ih, il, out);
  softmax_rows<<<dim3(MTOT), 256, 0, stream>>>(out);
}

// Round 2
// 1107.109 us; speedup vs baseline: 1.4951x; 1.4951x over previous
//
#include <hip/hip_runtime.h>
#include <hip/hip_bf16.h>
#include <stdint.h>

#define DM   1024
#define BATCH 4
#define SEQ  4096
#define MTOT (BATCH*SEQ)   // 16384

typedef __attribute__((ext_vector_type(8))) short bf16x8;
typedef __attribute__((ext_vector_type(4))) float f32x4;

// async global->LDS, 16B per lane; LDS dest = uniform base + lane*16
#define GLOAD_LDS16(gp, lp) __builtin_amdgcn_global_load_lds( \
    (const __attribute__((address_space(1))) unsigned int*)(gp), \
    (__attribute__((address_space(3))) unsigned int*)(lp), 16, 0, 0)

// f32 -> bf16 bits, round-to-nearest-even
__device__ __forceinline__ ushort f2bf(float f){
  uint u = __float_as_uint(f);
  u += 0x7FFFu + ((u >> 16) & 1u);
  return (ushort)(u >> 16);
}
__device__ __forceinline__ float bf2f(ushort b){ return __uint_as_float(((uint)b) << 16); }

__device__ __forceinline__ void split4(const float4 v, ushort4& h4, ushort4& l4){
  h4.x = f2bf(v.x); l4.x = f2bf(v.x - bf2f(h4.x));
  h4.y = f2bf(v.y); l4.y = f2bf(v.y - bf2f(h4.y));
  h4.z = f2bf(v.z); l4.z = f2bf(v.z - bf2f(h4.z));
  h4.w = f2bf(v.w); l4.w = f2bf(v.w - bf2f(h4.w));
}

// ---------------------------------------------------------------------------
// prep_w: transpose w[k][n] -> wt[n][k], split into bf16 hi/lo planes.
// ---------------------------------------------------------------------------
__global__ __launch_bounds__(256)
void prep_w(const float* __restrict__ w1, const float* __restrict__ w2,
            ushort* __restrict__ wt1h, ushort* __restrict__ wt1l,
            ushort* __restrict__ wt2h, ushort* __restrict__ wt2l){
  __shared__ float s[32][33];
  const float* w = blockIdx.z ? w2 : w1;
  ushort* oh = blockIdx.z ? wt2h : wt1h;
  ushort* ol = blockIdx.z ? wt2l : wt1l;
  const int n0 = blockIdx.x * 32, k0 = blockIdx.y * 32;
  const int tx = threadIdx.x & 31, ty = threadIdx.x >> 5;
  for (int r = 0; r < 4; r++){
    s[ty + r*8][tx] = w[(size_t)(k0 + ty + r*8) * DM + n0 + tx];
  }
  __syncthreads();
  for (int r = 0; r < 4; r++){
    int n = ty + r*8;
    float v = s[tx][n];
    ushort h = f2bf(v);
    float lo = v - bf2f(h);
    size_t o = (size_t)(n0 + n) * DM + k0 + tx;
    oh[o] = h;
    ol[o] = f2bf(lo);
  }
}

// ---------------------------------------------------------------------------
// gemm_xw: h = hidden @ w1 + b1 (z=0) ; i = (hidden+pre) @ w2 + b2 (z=1)
// A: f32 global -> split-bf16 manual staging (padded LDS, stride 40 ushorts).
// B: pre-split wt planes, async global_load_lds width=16.
// grid (8, 128, 2), block 256 (4 waves, 2x2 of 64x64).
// ---------------------------------------------------------------------------
#define ASTR 40   // padded A stride in ushorts (80 B = 5*16 -> b128-aligned)

__global__ __launch_bounds__(256, 2)
void gemm_xw(const float* __restrict__ hidden, const float* __restrict__ pre,
             const ushort* __restrict__ w1h, const ushort* __restrict__ w1l,
             const ushort* __restrict__ w2h, const ushort* __restrict__ w2l,
             const float* __restrict__ b1, const float* __restrict__ b2,
             ushort* __restrict__ hh, ushort* __restrict__ hl,
             ushort* __restrict__ ih, ushort* __restrict__ il){
  const int z = blockIdx.z;
  const ushort* wh = z ? w2h : w1h;
  const ushort* wl = z ? w2l : w1l;
  const float* bias = z ? b2 : b1;
  ushort* oh = z ? ih : hh;
  ushort* ol = z ? il : hl;
  const int m0 = blockIdx.y * 128, n0 = blockIdx.x * 128;

  __shared__ alignas(16) ushort Ah[128*ASTR];
  __shared__ alignas(16) ushort Al[128*ASTR];
  __shared__ alignas(16) ushort Bh[128*32];
  __shared__ alignas(16) ushort Bl[128*32];

  const int tid = threadIdx.x;
  const int lane = tid & 63, wid = tid >> 6;
  const int wm = (wid & 1) * 64, wn = (wid >> 1) * 64;
  const int lr = lane & 15, lk = (lane >> 4) * 8;

  // async B staging assignment: waves 0,1 -> Bh ; waves 2,3 -> Bl ; 4 insts each
  const ushort* bp = (wid < 2) ? wh : wl;
  ushort* blds = (wid < 2) ? Bh : Bl;
  const int tb = (wid & 1) * 4;
  // per-lane global offset pattern: 4 rows per inst group of 4 lanes
  const size_t bgoff = (size_t)(n0 + (lane >> 2)) * DM + (lane & 3) * 8;

  f32x4 acc[4][4];
  for (int i = 0; i < 4; i++) for (int j = 0; j < 4; j++) acc[i][j] = (f32x4){0.f,0.f,0.f,0.f};

  for (int k0 = 0; k0 < DM; k0 += 32){
    __syncthreads();
    // async B tile (16 insts across block)
    const ushort* gb = bp + bgoff + k0;
    #pragma unroll
    for (int t = 0; t < 4; t++){
      GLOAD_LDS16(gb + (size_t)(tb + t) * 16 * DM, blds + (tb + t) * 512);
    }
    // manual A tile: f32 load + split (overlaps with async B)
    #pragma unroll
    for (int c = 0; c < 4; c++){
      int idx = c * 256 + tid;
      int row = idx >> 3, kq = (idx & 7) * 4;
      size_t ga = (size_t)(m0 + row) * DM + k0 + kq;
      float4 v = *(const float4*)&hidden[ga];
      if (z){
        float4 p = *(const float4*)&pre[ga];
        v.x += p.x; v.y += p.y; v.z += p.z; v.w += p.w;
      }
      ushort4 h4, l4;
      split4(v, h4, l4);
      *(ushort4*)&Ah[row*ASTR + kq] = h4;
      *(ushort4*)&Al[row*ASTR + kq] = l4;
    }
    __syncthreads();

    bf16x8 fah[4], fal[4], fbh[4], fbl[4];
    #pragma unroll
    for (int i = 0; i < 4; i++){
      fah[i] = *(const bf16x8*)&Ah[(wm + i*16 + lr)*ASTR + lk];
      fal[i] = *(const bf16x8*)&Al[(wm + i*16 + lr)*ASTR + lk];
      fbh[i] = *(const bf16x8*)&Bh[(wn + i*16 + lr)*32 + lk];
      fbl[i] = *(const bf16x8*)&Bl[(wn + i*16 + lr)*32 + lk];
    }
    #pragma unroll
    for (int i = 0; i < 4; i++)
      #pragma unroll
      for (int j = 0; j < 4; j++){
        acc[i][j] = __builtin_amdgcn_mfma_f32_16x16x32_bf16(fah[i], fbh[j], acc[i][j], 0, 0, 0);
        acc[i][j] = __builtin_amdgcn_mfma_f32_16x16x32_bf16(fah[i], fbl[j], acc[i][j], 0, 0, 0);
        acc[i][j] = __builtin_amdgcn_mfma_f32_16x16x32_bf16(fal[i], fbh[j], acc[i][j], 0, 0, 0);
      }
  }

  const int rbase = (lane >> 4) * 4;
  #pragma unroll
  for (int i = 0; i < 4; i++)
    #pragma unroll
    for (int j = 0; j < 4; j++){
      int gc = n0 + wn + j*16 + lr;
      float bv = bias[gc];
      #pragma unroll
      for (int r = 0; r < 4; r++){
        int gr = m0 + wm + i*16 + rbase + r;
        float v = acc[i][j][r] + bv;
        ushort hb = f2bf(v);
        size_t o = (size_t)gr * DM + gc;
        oh[o] = hb;
        ol[o] = f2bf(v - bf2f(hb));
      }
    }
}

// ---------------------------------------------------------------------------
// gemm_scores: out[b,q,k] = sum_d h[b,q,d] * i[b,k,d]  (raw logits, f32)
// All 4 planes staged via async global_load_lds (one plane per wave, 8 insts).
// grid (32,32,4), block 256.
// ---------------------------------------------------------------------------
__global__ __launch_bounds__(256, 2)
void gemm_scores(const ushort* __restrict__ hh, const ushort* __restrict__ hl,
                 const ushort* __restrict__ ih, const ushort* __restrict__ il,
                 float* __restrict__ out){
  const int b = blockIdx.z;
  const int m0 = blockIdx.y * 128, n0 = blockIdx.x * 128;
  const size_t abase = (size_t)b * SEQ * DM;

  __shared__ alignas(16) ushort Ah[128*32];
  __shared__ alignas(16) ushort Al[128*32];
  __shared__ alignas(16) ushort Bh[128*32];
  __shared__ alignas(16) ushort Bl[128*32];

  const int tid = threadIdx.x;
  const int lane = tid & 63, wid = tid >> 6;
  const int wm = (wid & 1) * 64, wn = (wid >> 1) * 64;
  const int lr = lane & 15, lk = (lane >> 4) * 8;

  // one plane per wave
  const ushort* plane = (wid == 0) ? hh : (wid == 1) ? hl : (wid == 2) ? ih : il;
  ushort* lds = (wid == 0) ? Ah : (wid == 1) ? Al : (wid == 2) ? Bh : Bl;
  const int r0 = (wid < 2) ? m0 : n0;
  const size_t goff = abase + (size_t)(r0 + (lane >> 2)) * DM + (lane & 3) * 8;

  f32x4 acc[4][4];
  for (int i = 0; i < 4; i++) for (int j = 0; j < 4; j++) acc[i][j] = (f32x4){0.f,0.f,0.f,0.f};

  for (int k0 = 0; k0 < DM; k0 += 32){
    __syncthreads();
    const ushort* gp = plane + goff + k0;
    #pragma unroll
    for (int t = 0; t < 8; t++){
      GLOAD_LDS16(gp + (size_t)t * 16 * DM, lds + t * 512);
    }
    __syncthreads();

    bf16x8 fah[4], fal[4], fbh[4], fbl[4];
    #pragma unroll
    for (int i = 0; i < 4; i++){
      fah[i] = *(const bf16x8*)&Ah[(wm + i*16 + lr)*32 + lk];
      fal[i] = *(const bf16x8*)&Al[(wm + i*16 + lr)*32 + lk];
      fbh[i] = *(const bf16x8*)&Bh[(wn + i*16 + lr)*32 + lk];
      fbl[i] = *(const bf16x8*)&Bl[(wn + i*16 + lr)*32 + lk];
    }
    #pragma unroll
    for (int i = 0; i < 4; i++)
      #pragma unroll
      for (int j = 0; j < 4; j++){
        acc[i][j] = __builtin_amdgcn_mfma_f32_16x16x32_bf16(fah[i], fbh[j], acc[i][j], 0, 0, 0);
        acc[i][j] = __builtin_amdgcn_mfma_f32_16x16x32_bf16(fah[i], fbl[j], acc[i][j], 0, 0, 0);
        acc[i][j] = __builtin_amdgcn_mfma_f32_16x16x32_bf16(fal[i], fbh[j], acc[i][j], 0, 0, 0);
      }
  }

  const int rbase = (lane >> 4) * 4;
  #pragma unroll
  for (int i = 0; i < 4; i++)
    #pragma unroll
    for (int j = 0; j < 4; j++){
      int gc = n0 + wn + j*16 + lr;
      #pragma unroll
      for (int r = 0; r < 4; r++){
        int gr = m0 + wm + i*16 + rbase + r;
        out[((size_t)b * SEQ + gr) * SEQ + gc] = acc[i][j][r];
      }
    }
}

// ---------------------------------------------------------------------------
// softmax_rows: in-place row softmax over last dim (4096). One block per row.
// ---------------------------------------------------------------------------
__global__ __launch_bounds__(256)
void softmax_rows(float* __restrict__ out){
  __shared__ float red[256];
  const size_t row = blockIdx.x;
  float* p = out + row * (size_t)SEQ;
  const int tid = threadIdx.x;

  float4 v[4];
  float m = -3.0e38f;
  #pragma unroll
  for (int c = 0; c < 4; c++){
    v[c] = ((const float4*)p)[c*256 + tid];
    m = fmaxf(m, fmaxf(fmaxf(v[c].x, v[c].y), fmaxf(v[c].z, v[c].w)));
  }
  red[tid] = m; __syncthreads();
  for (int o = 128; o > 0; o >>= 1){
    if (tid < o) red[tid] = fmaxf(red[tid], red[tid + o]);
    __syncthreads();
  }
  const float M = red[0];
  __syncthreads();

  float s = 0.f;
  #pragma unroll
  for (int c = 0; c < 4; c++){
    v[c].x = __expf(v[c].x - M); s += v[c].x;
    v[c].y = __expf(v[c].y - M); s += v[c].y;
    v[c].z = __expf(v[c].z - M); s += v[c].z;
    v[c].w = __expf(v[c].w - M); s += v[c].w;
  }
  red[tid] = s; __syncthreads();
  for (int o = 128; o > 0; o >>= 1){
    if (tid < o) red[tid] += red[tid + o];
    __syncthreads();
  }
  const float inv = 1.0f / red[0];
  #pragma unroll
  for (int c = 0; c < 4; c++){
    v[c].x *= inv; v[c].y *= inv; v[c].z *= inv; v[c].w *= inv;
    ((float4*)p)[c*256 + tid] = v[c];
  }
}

// ---------------------------------------------------------------------------
extern "C" void kernel_launch(void* const* d_in, const int* in_sizes, int n_in,
                              void* d_out, int out_size, void* d_ws, size_t ws_size,
                              hipStream_t stream){
  const float* hidden = (const float*)d_in[0];
  const float* pre    = (const float*)d_in[1];
  const float* w1     = (const float*)d_in[2];
  const float* b1     = (const float*)d_in[3];
  const float* w2     = (const float*)d_in[4];
  const float* b2     = (const float*)d_in[5];
  float* out = (float*)d_out;

  char* ws = (char*)d_ws;
  const size_t WPLANE = (size_t)DM * DM * sizeof(ushort);     // 2 MiB
  const size_t APLANE = (size_t)MTOT * DM * sizeof(ushort);   // 32 MiB
  ushort* w1h = (ushort*)(ws + 0*WPLANE);
  ushort* w1l = (ushort*)(ws + 1*WPLANE);
  ushort* w2h = (ushort*)(ws + 2*WPLANE);
  ushort* w2l = (ushort*)(ws + 3*WPLANE);
  char* act = ws + 4*WPLANE;
  ushort* hh = (ushort*)(act + 0*APLANE);
  ushort* hl = (ushort*)(act + 1*APLANE);
  ushort* ih = (ushort*)(act + 2*APLANE);
  ushort* il = (ushort*)(act + 3*APLANE);

  prep_w<<<dim3(32, 32, 2), 256, 0, stream>>>(w1, w2, w1h, w1l, w2h, w2l);
  gemm_xw<<<dim3(DM/128, MTOT/128, 2), 256, 0, stream>>>(
      hidden, pre, w1h, w1l, w2h, w2l, b1, b2, hh, hl, ih, il);
  gemm_scores<<<dim3(SEQ/128, SEQ/128, BATCH), 256, 0, stream>>>(hh, hl, ih, il, out);
  softmax_rows<<<dim3(MTOT), 256, 0, stream>>>(out);
}

// Round 3
// 956.606 us; speedup vs baseline: 1.7304x; 1.1573x over previous
//
#include <hip/hip_runtime.h>
#include <hip/hip_bf16.h>
#include <stdint.h>

#define DM   1024
#define BATCH 4
#define SEQ  4096
#define MTOT (BATCH*SEQ)   // 16384

typedef __attribute__((ext_vector_type(8))) short bf16x8;
typedef __attribute__((ext_vector_type(4))) float f32x4;

// async global->LDS, 16B per lane; LDS dest = uniform base + lane*16
#define GLOAD_LDS16(gp, lp) __builtin_amdgcn_global_load_lds( \
    (const __attribute__((address_space(1))) unsigned int*)(gp), \
    (__attribute__((address_space(3))) unsigned int*)(lp), 16, 0, 0)

// f32 -> bf16 bits, round-to-nearest-even
__device__ __forceinline__ ushort f2bf(float f){
  uint u = __float_as_uint(f);
  u += 0x7FFFu + ((u >> 16) & 1u);
  return (ushort)(u >> 16);
}
__device__ __forceinline__ float bf2f(ushort b){ return __uint_as_float(((uint)b) << 16); }

__device__ __forceinline__ void split4(const float4 v, ushort4& h4, ushort4& l4){
  h4.x = f2bf(v.x); l4.x = f2bf(v.x - bf2f(h4.x));
  h4.y = f2bf(v.y); l4.y = f2bf(v.y - bf2f(h4.y));
  h4.z = f2bf(v.z); l4.z = f2bf(v.z - bf2f(h4.z));
  h4.w = f2bf(v.w); l4.w = f2bf(v.w - bf2f(h4.w));
}

// ---------------------------------------------------------------------------
// prep_w_split: elementwise split W1,W2 (row-major, no transpose needed:
// Gt = W2 @ W1^T consumes both with the e index contiguous).
// grid (1024, 2), block 256, 4 f32/thread.
// ---------------------------------------------------------------------------
__global__ __launch_bounds__(256)
void prep_w_split(const float* __restrict__ w1, const float* __restrict__ w2,
                  ushort* __restrict__ w1h, ushort* __restrict__ w1l,
                  ushort* __restrict__ w2h, ushort* __restrict__ w2l){
  const float* w = blockIdx.y ? w2 : w1;
  ushort* oh = blockIdx.y ? w2h : w1h;
  ushort* ol = blockIdx.y ? w2l : w1l;
  size_t off = ((size_t)blockIdx.x * 256 + threadIdx.x) * 4;
  float4 v = *(const float4*)&w[off];
  ushort4 h4, l4; split4(v, h4, l4);
  *(ushort4*)&oh[off] = h4;
  *(ushort4*)&ol[off] = l4;
}

// ---------------------------------------------------------------------------
// prep_xy: X = hidden, Y = hidden + pre. Split to bf16 planes once.
// grid (16384), block 256, 4 elems/thread. writeX=0 skips X planes.
// ---------------------------------------------------------------------------
__global__ __launch_bounds__(256)
void prep_xy(const float* __restrict__ hidden, const float* __restrict__ pre,
             ushort* __restrict__ xh, ushort* __restrict__ xl,
             ushort* __restrict__ yh, ushort* __restrict__ yl, int writeX){
  size_t off = ((size_t)blockIdx.x * 256 + threadIdx.x) * 4;
  float4 h = *(const float4*)&hidden[off];
  float4 p = *(const float4*)&pre[off];
  float4 y = {h.x + p.x, h.y + p.y, h.z + p.z, h.w + p.w};
  ushort4 a, b;
  if (writeX){
    split4(h, a, b);
    *(ushort4*)&xh[off] = a;
    *(ushort4*)&xl[off] = b;
  }
  split4(y, a, b);
  *(ushort4*)&yh[off] = a;
  *(ushort4*)&yl[off] = b;
}

// ---------------------------------------------------------------------------
// c2k: c2 = W2 @ b1  (c2[f] = sum_e W2[f,e] b1[e]). One wave per row.
// grid (256), block 256.
// ---------------------------------------------------------------------------
__global__ __launch_bounds__(256)
void c2k(const float* __restrict__ w2, const float* __restrict__ b1,
         float* __restrict__ c2){
  const int wid = threadIdx.x >> 6, lane = threadIdx.x & 63;
  const int row = blockIdx.x * 4 + wid;
  float s = 0.f;
  #pragma unroll
  for (int t = 0; t < 16; t++){
    int e = lane + 64 * t;
    s += w2[(size_t)row * DM + e] * b1[e];
  }
  #pragma unroll
  for (int o = 32; o > 0; o >>= 1) s += __shfl_xor(s, o, 64);
  if (lane == 0) c2[row] = s;
}

// ---------------------------------------------------------------------------
// betak: beta[r] = sum_f (Yh+Yl)[r,f] * c2[f]. One wave per row.
// grid (4096), block 256.
// ---------------------------------------------------------------------------
__global__ __launch_bounds__(256)
void betak(const ushort* __restrict__ yh, const ushort* __restrict__ yl,
           const float* __restrict__ c2, float* __restrict__ beta){
  const int wid = threadIdx.x >> 6, lane = threadIdx.x & 63;
  const size_t r = (size_t)blockIdx.x * 4 + wid;
  const size_t base = r * DM + lane * 16;
  float s = 0.f;
  #pragma unroll
  for (int q = 0; q < 2; q++){
    bf16x8 h = *(const bf16x8*)&yh[base + q * 8];
    bf16x8 l = *(const bf16x8*)&yl[base + q * 8];
    float4 c0 = *(const float4*)&c2[lane * 16 + q * 8];
    float4 c1 = *(const float4*)&c2[lane * 16 + q * 8 + 4];
    s += (bf2f((ushort)h[0]) + bf2f((ushort)l[0])) * c0.x;
    s += (bf2f((ushort)h[1]) + bf2f((ushort)l[1])) * c0.y;
    s += (bf2f((ushort)h[2]) + bf2f((ushort)l[2])) * c0.z;
    s += (bf2f((ushort)h[3]) + bf2f((ushort)l[3])) * c0.w;
    s += (bf2f((ushort)h[4]) + bf2f((ushort)l[4])) * c1.x;
    s += (bf2f((ushort)h[5]) + bf2f((ushort)l[5])) * c1.y;
    s += (bf2f((ushort)h[6]) + bf2f((ushort)l[6])) * c1.z;
    s += (bf2f((ushort)h[7]) + bf2f((ushort)l[7])) * c1.w;
  }
  #pragma unroll
  for (int o = 32; o > 0; o >>= 1) s += __shfl_xor(s, o, 64);
  if (lane == 0) beta[r] = s;
}

// ---------------------------------------------------------------------------
// Shared split-bf16 B^T main loop: acc += A(m0..+128) @ B(n0..+128)^T over
// K=1024, all 4 planes async-staged (one plane per wave, 8 insts each).
// ---------------------------------------------------------------------------
__device__ __forceinline__ void bt_mainloop(
    const ushort* __restrict__ Aph, const ushort* __restrict__ Apl,
    const ushort* __restrict__ Bph, const ushort* __restrict__ Bpl,
    int m0, int n0, f32x4 (&acc)[4][4]){
  __shared__ alignas(16) ushort Ah[128*32];
  __shared__ alignas(16) ushort Al[128*32];
  __shared__ alignas(16) ushort Bh[128*32];
  __shared__ alignas(16) ushort Bl[128*32];

  const int tid = threadIdx.x;
  const int lane = tid & 63, wid = tid >> 6;
  const int wm = (wid & 1) * 64, wn = (wid >> 1) * 64;
  const int lr = lane & 15, lk = (lane >> 4) * 8;

  const ushort* plane = (wid == 0) ? Aph : (wid == 1) ? Apl : (wid == 2) ? Bph : Bpl;
  ushort* lds = (wid == 0) ? Ah : (wid == 1) ? Al : (wid == 2) ? Bh : Bl;
  const int r0 = (wid < 2) ? m0 : n0;
  const size_t goff = (size_t)(r0 + (lane >> 2)) * DM + (lane & 3) * 8;

  for (int k0 = 0; k0 < DM; k0 += 32){
    __syncthreads();
    const ushort* gp = plane + goff + k0;
    #pragma unroll
    for (int t = 0; t < 8; t++){
      GLOAD_LDS16(gp + (size_t)t * 16 * DM, lds + t * 512);
    }
    __syncthreads();

    bf16x8 fah[4], fal[4], fbh[4], fbl[4];
    #pragma unroll
    for (int i = 0; i < 4; i++){
      fah[i] = *(const bf16x8*)&Ah[(wm + i*16 + lr)*32 + lk];
      fal[i] = *(const bf16x8*)&Al[(wm + i*16 + lr)*32 + lk];
      fbh[i] = *(const bf16x8*)&Bh[(wn + i*16 + lr)*32 + lk];
      fbl[i] = *(const bf16x8*)&Bl[(wn + i*16 + lr)*32 + lk];
    }
    #pragma unroll
    for (int i = 0; i < 4; i++)
      #pragma unroll
      for (int j = 0; j < 4; j++){
        acc[i][j] = __builtin_amdgcn_mfma_f32_16x16x32_bf16(fah[i], fbh[j], acc[i][j], 0, 0, 0);
        acc[i][j] = __builtin_amdgcn_mfma_f32_16x16x32_bf16(fah[i], fbl[j], acc[i][j], 0, 0, 0);
        acc[i][j] = __builtin_amdgcn_mfma_f32_16x16x32_bf16(fal[i], fbh[j], acc[i][j], 0, 0, 0);
      }
  }
}

// gemm_bt_split: out planes = split(A @ B^T). Used for Gt (grid 8x8) and
// Z (grid 8x128). Out row stride = DM.
__global__ __launch_bounds__(256, 2)
void gemm_bt_split(const ushort* __restrict__ Aph, const ushort* __restrict__ Apl,
                   const ushort* __restrict__ Bph, const ushort* __restrict__ Bpl,
                   ushort* __restrict__ oh, ushort* __restrict__ ol){
  const int m0 = blockIdx.y * 128, n0 = blockIdx.x * 128;
  f32x4 acc[4][4];
  for (int i = 0; i < 4; i++) for (int j = 0; j < 4; j++) acc[i][j] = (f32x4){0.f,0.f,0.f,0.f};
  bt_mainloop(Aph, Apl, Bph, Bpl, m0, n0, acc);

  const int lane = threadIdx.x & 63, wid = threadIdx.x >> 6;
  const int wm = (wid & 1) * 64, wn = (wid >> 1) * 64;
  const int lr = lane & 15;
  const int rbase = (lane >> 4) * 4;
  #pragma unroll
  for (int i = 0; i < 4; i++)
    #pragma unroll
    for (int j = 0; j < 4; j++){
      int gc = n0 + wn + j*16 + lr;
      #pragma unroll
      for (int r = 0; r < 4; r++){
        int gr = m0 + wm + i*16 + rbase + r;
        float v = acc[i][j][r];
        ushort hb = f2bf(v);
        size_t o = (size_t)gr * DM + gc;
        oh[o] = hb;
        ol[o] = f2bf(v - bf2f(hb));
      }
    }
}

// gemm_bt_f32: out[b,q,k] = Z[b,q,:] . Y[b,k,:]  (raw logits, f32)
// grid (32,32,4), block 256.
__global__ __launch_bounds__(256, 2)
void gemm_bt_f32(const ushort* __restrict__ Aph, const ushort* __restrict__ Apl,
                 const ushort* __restrict__ Bph, const ushort* __restrict__ Bpl,
                 float* __restrict__ out){
  const int b = blockIdx.z;
  const int m0 = blockIdx.y * 128, n0 = blockIdx.x * 128;
  const size_t abase = (size_t)b * SEQ * DM;
  f32x4 acc[4][4];
  for (int i = 0; i < 4; i++) for (int j = 0; j < 4; j++) acc[i][j] = (f32x4){0.f,0.f,0.f,0.f};
  bt_mainloop(Aph + abase, Apl + abase, Bph + abase, Bpl + abase, m0, n0, acc);

  const int lane = threadIdx.x & 63, wid = threadIdx.x >> 6;
  const int wm = (wid & 1) * 64, wn = (wid >> 1) * 64;
  const int lr = lane & 15;
  const int rbase = (lane >> 4) * 4;
  #pragma unroll
  for (int i = 0; i < 4; i++)
    #pragma unroll
    for (int j = 0; j < 4; j++){
      int gc = n0 + wn + j*16 + lr;
      #pragma unroll
      for (int r = 0; r < 4; r++){
        int gr = m0 + wm + i*16 + rbase + r;
        out[((size_t)b * SEQ + gr) * SEQ + gc] = acc[i][j][r];
      }
    }
}

// ---------------------------------------------------------------------------
// gemm_z_manual (compact-ws fallback): Z = split(hidden @ Gt^T), A staged
// manually from f32 (split in VALU), B async. grid (8,128).
// ---------------------------------------------------------------------------
#define ASTR 40
__global__ __launch_bounds__(256, 2)
void gemm_z_manual(const float* __restrict__ hidden,
                   const ushort* __restrict__ gth, const ushort* __restrict__ gtl,
                   ushort* __restrict__ zh, ushort* __restrict__ zl){
  const int m0 = blockIdx.y * 128, n0 = blockIdx.x * 128;
  __shared__ alignas(16) ushort Ah[128*ASTR];
  __shared__ alignas(16) ushort Al[128*ASTR];
  __shared__ alignas(16) ushort Bh[128*32];
  __shared__ alignas(16) ushort Bl[128*32];

  const int tid = threadIdx.x;
  const int lane = tid & 63, wid = tid >> 6;
  const int wm = (wid & 1) * 64, wn = (wid >> 1) * 64;
  const int lr = lane & 15, lk = (lane >> 4) * 8;

  const ushort* bp = (wid < 2) ? gth : gtl;
  ushort* blds = (wid < 2) ? Bh : Bl;
  const int tb = (wid & 1) * 4;
  const size_t bgoff = (size_t)(n0 + (lane >> 2)) * DM + (lane & 3) * 8;

  f32x4 acc[4][4];
  for (int i = 0; i < 4; i++) for (int j = 0; j < 4; j++) acc[i][j] = (f32x4){0.f,0.f,0.f,0.f};

  for (int k0 = 0; k0 < DM; k0 += 32){
    __syncthreads();
    const ushort* gb = bp + bgoff + k0;
    #pragma unroll
    for (int t = 0; t < 4; t++){
      GLOAD_LDS16(gb + (size_t)(tb + t) * 16 * DM, blds + (tb + t) * 512);
    }
    #pragma unroll
    for (int c = 0; c < 4; c++){
      int idx = c * 256 + tid;
      int row = idx >> 3, kq = (idx & 7) * 4;
      size_t ga = (size_t)(m0 + row) * DM + k0 + kq;
      float4 v = *(const float4*)&hidden[ga];
      ushort4 h4, l4;
      split4(v, h4, l4);
      *(ushort4*)&Ah[row*ASTR + kq] = h4;
      *(ushort4*)&Al[row*ASTR + kq] = l4;
    }
    __syncthreads();

    bf16x8 fah[4], fal[4], fbh[4], fbl[4];
    #pragma unroll
    for (int i = 0; i < 4; i++){
      fah[i] = *(const bf16x8*)&Ah[(wm + i*16 + lr)*ASTR + lk];
      fal[i] = *(const bf16x8*)&Al[(wm + i*16 + lr)*ASTR + lk];
      fbh[i] = *(const bf16x8*)&Bh[(wn + i*16 + lr)*32 + lk];
      fbl[i] = *(const bf16x8*)&Bl[(wn + i*16 + lr)*32 + lk];
    }
    #pragma unroll
    for (int i = 0; i < 4; i++)
      #pragma unroll
      for (int j = 0; j < 4; j++){
        acc[i][j] = __builtin_amdgcn_mfma_f32_16x16x32_bf16(fah[i], fbh[j], acc[i][j], 0, 0, 0);
        acc[i][j] = __builtin_amdgcn_mfma_f32_16x16x32_bf16(fah[i], fbl[j], acc[i][j], 0, 0, 0);
        acc[i][j] = __builtin_amdgcn_mfma_f32_16x16x32_bf16(fal[i], fbh[j], acc[i][j], 0, 0, 0);
      }
  }

  const int rbase = (lane >> 4) * 4;
  #pragma unroll
  for (int i = 0; i < 4; i++)
    #pragma unroll
    for (int j = 0; j < 4; j++){
      int gc = n0 + wn + j*16 + lr;
      #pragma unroll
      for (int r = 0; r < 4; r++){
        int gr = m0 + wm + i*16 + rbase + r;
        float v = acc[i][j][r];
        ushort hb = f2bf(v);
        size_t o = (size_t)gr * DM + gc;
        zh[o] = hb;
        zl[o] = f2bf(v - bf2f(hb));
      }
    }
}

// ---------------------------------------------------------------------------
// softmax_rows: in-place row softmax over last dim (4096), + beta[k] column
// bias pre-add. Shuffle reductions, 2 barriers. One block per row.
// ---------------------------------------------------------------------------
__global__ __launch_bounds__(256)
void softmax_rows(float* __restrict__ out, const float* __restrict__ beta){
  __shared__ float red[8];
  const size_t row = blockIdx.x;
  float* p = out + row * (size_t)SEQ;
  const float* bp = beta + ((row >> 12) << 12);
  const int tid = threadIdx.x, lane = tid & 63, wid = tid >> 6;

  float4 v[4];
  float m = -3.0e38f;
  #pragma unroll
  for (int c = 0; c < 4; c++){
    v[c] = ((const float4*)p)[c*256 + tid];
    float4 bb = ((const float4*)bp)[c*256 + tid];
    v[c].x += bb.x; v[c].y += bb.y; v[c].z += bb.z; v[c].w += bb.w;
    m = fmaxf(m, fmaxf(fmaxf(v[c].x, v[c].y), fmaxf(v[c].z, v[c].w)));
  }
  #pragma unroll
  for (int o = 32; o > 0; o >>= 1) m = fmaxf(m, __shfl_xor(m, o, 64));
  if (lane == 0) red[wid] = m;
  __syncthreads();
  const float M = fmaxf(fmaxf(red[0], red[1]), fmaxf(red[2], red[3]));

  float s = 0.f;
  #pragma unroll
  for (int c = 0; c < 4; c++){
    v[c].x = __expf(v[c].x - M); s += v[c].x;
    v[c].y = __expf(v[c].y - M); s += v[c].y;
    v[c].z = __expf(v[c].z - M); s += v[c].z;
    v[c].w = __expf(v[c].w - M); s += v[c].w;
  }
  #pragma unroll
  for (int o = 32; o > 0; o >>= 1) s += __shfl_xor(s, o, 64);
  if (lane == 0) red[4 + wid] = s;
  __syncthreads();
  const float inv = 1.0f / (red[4] + red[5] + red[6] + red[7]);
  #pragma unroll
  for (int c = 0; c < 4; c++){
    v[c].x *= inv; v[c].y *= inv; v[c].z *= inv; v[c].w *= inv;
    ((float4*)p)[c*256 + tid] = v[c];
  }
}

// ---------------------------------------------------------------------------
extern "C" void kernel_launch(void* const* d_in, const int* in_sizes, int n_in,
                              void* d_out, int out_size, void* d_ws, size_t ws_size,
                              hipStream_t stream){
  const float* hidden = (const float*)d_in[0];
  const float* pre    = (const float*)d_in[1];
  const float* w1     = (const float*)d_in[2];
  const float* b1     = (const float*)d_in[3];
  const float* w2     = (const float*)d_in[4];
  // b2 unused: its contribution is constant per softmax row and cancels.
  float* out = (float*)d_out;

  char* ws = (char*)d_ws;
  const size_t WP = (size_t)DM * DM * sizeof(ushort);     // 2 MiB
  const size_t AP = (size_t)MTOT * DM * sizeof(ushort);   // 32 MiB
  const bool big = ws_size >= 6*AP + 6*WP + (1u << 20);

  ushort *w1h, *w1l, *w2h, *w2l, *Gth, *Gtl, *Xh, *Xl, *Yh, *Yl, *Zh, *Zl;
  float *c2, *beta;
  if (big){
    Xh  = (ushort*)(ws + 0*AP);  Xl  = (ushort*)(ws + 1*AP);
    Yh  = (ushort*)(ws + 2*AP);  Yl  = (ushort*)(ws + 3*AP);
    Zh  = (ushort*)(ws + 4*AP);  Zl  = (ushort*)(ws + 5*AP);
    w1h = (ushort*)(ws + 6*AP);          w1l = (ushort*)(ws + 6*AP + WP);
    w2h = (ushort*)(ws + 6*AP + 2*WP);   w2l = (ushort*)(ws + 6*AP + 3*WP);
    Gth = (ushort*)(ws + 6*AP + 4*WP);   Gtl = (ushort*)(ws + 6*AP + 5*WP);
    c2   = (float*)(ws + 6*AP + 6*WP);
    beta = c2 + DM;
  } else {
    // compact: W planes alias the (not-yet-written) Z region
    Zh  = (ushort*)(ws + 0*AP);  Zl  = (ushort*)(ws + 1*AP);
    Yh  = (ushort*)(ws + 2*AP);  Yl  = (ushort*)(ws + 3*AP);
    Gth = (ushort*)(ws + 4*AP);  Gtl = (ushort*)(ws + 4*AP + WP);
    w1h = (ushort*)(ws + 0);       w1l = (ushort*)(ws + WP);
    w2h = (ushort*)(ws + 2*WP);    w2l = (ushort*)(ws + 3*WP);
    c2   = (float*)(ws + 4*AP + 2*WP);
    beta = c2 + DM;
    Xh = Xl = nullptr;
  }

  prep_w_split<<<dim3(1024, 2), 256, 0, stream>>>(w1, w2, w1h, w1l, w2h, w2l);
  prep_xy<<<dim3(16384), 256, 0, stream>>>(hidden, pre, Xh, Xl, Yh, Yl, big ? 1 : 0);
  c2k<<<dim3(256), 256, 0, stream>>>(w2, b1, c2);
  // Gt = W2 @ W1^T  (so Z = X @ Gt^T = X @ W1 @ W2^T)
  gemm_bt_split<<<dim3(8, 8), 256, 0, stream>>>(w2h, w2l, w1h, w1l, Gth, Gtl);
  if (big){
    gemm_bt_split<<<dim3(8, 128), 256, 0, stream>>>(Xh, Xl, Gth, Gtl, Zh, Zl);
  } else {
    gemm_z_manual<<<dim3(8, 128), 256, 0, stream>>>(hidden, Gth, Gtl, Zh, Zl);
  }
  betak<<<dim3(4096), 256, 0, stream>>>(Yh, Yl, c2, beta);
  gemm_bt_f32<<<dim3(32, 32, 4), 256, 0, stream>>>(Zh, Zl, Yh, Yl, out);
  softmax_rows<<<dim3(MTOT), 256, 0, stream>>>(out, beta);
}

// Round 5
// 945.321 us; speedup vs baseline: 1.7510x; 1.0119x over previous
//
#include <hip/hip_runtime.h>
#include <hip/hip_bf16.h>
#include <stdint.h>

#define DM   1024
#define BATCH 4
#define SEQ  4096
#define MTOT (BATCH*SEQ)   // 16384

typedef __attribute__((ext_vector_type(8))) short bf16x8;
typedef __attribute__((ext_vector_type(4))) float f32x4;

// async global->LDS, 16B per lane; LDS dest = uniform base + lane*16
#define GLOAD_LDS16(gp, lp) __builtin_amdgcn_global_load_lds( \
    (const __attribute__((address_space(1))) unsigned int*)(gp), \
    (__attribute__((address_space(3))) unsigned int*)(lp), 16, 0, 0)

// f32 -> bf16 bits, round-to-nearest-even
__device__ __forceinline__ ushort f2bf(float f){
  uint u = __float_as_uint(f);
  u += 0x7FFFu + ((u >> 16) & 1u);
  return (ushort)(u >> 16);
}
__device__ __forceinline__ float bf2f(ushort b){ return __uint_as_float(((uint)b) << 16); }

__device__ __forceinline__ void split4(const float4 v, ushort4& h4, ushort4& l4){
  h4.x = f2bf(v.x); l4.x = f2bf(v.x - bf2f(h4.x));
  h4.y = f2bf(v.y); l4.y = f2bf(v.y - bf2f(h4.y));
  h4.z = f2bf(v.z); l4.z = f2bf(v.z - bf2f(h4.z));
  h4.w = f2bf(v.w); l4.w = f2bf(v.w - bf2f(h4.w));
}

// ---------------------------------------------------------------------------
// prep_w_split: elementwise split W1,W2 into bf16 hi/lo planes.
// ---------------------------------------------------------------------------
__global__ __launch_bounds__(256)
void prep_w_split(const float* __restrict__ w1, const float* __restrict__ w2,
                  ushort* __restrict__ w1h, ushort* __restrict__ w1l,
                  ushort* __restrict__ w2h, ushort* __restrict__ w2l){
  const float* w = blockIdx.y ? w2 : w1;
  ushort* oh = blockIdx.y ? w2h : w1h;
  ushort* ol = blockIdx.y ? w2l : w1l;
  size_t off = ((size_t)blockIdx.x * 256 + threadIdx.x) * 4;
  float4 v = *(const float4*)&w[off];
  ushort4 h4, l4; split4(v, h4, l4);
  *(ushort4*)&oh[off] = h4;
  *(ushort4*)&ol[off] = l4;
}

// ---------------------------------------------------------------------------
// prep_xy: X = hidden, Y = hidden + pre. Split to bf16 planes once.
// ---------------------------------------------------------------------------
__global__ __launch_bounds__(256)
void prep_xy(const float* __restrict__ hidden, const float* __restrict__ pre,
             ushort* __restrict__ xh, ushort* __restrict__ xl,
             ushort* __restrict__ yh, ushort* __restrict__ yl, int writeX){
  size_t off = ((size_t)blockIdx.x * 256 + threadIdx.x) * 4;
  float4 h = *(const float4*)&hidden[off];
  float4 p = *(const float4*)&pre[off];
  float4 y = {h.x + p.x, h.y + p.y, h.z + p.z, h.w + p.w};
  ushort4 a, b;
  if (writeX){
    split4(h, a, b);
    *(ushort4*)&xh[off] = a;
    *(ushort4*)&xl[off] = b;
  }
  split4(y, a, b);
  *(ushort4*)&yh[off] = a;
  *(ushort4*)&yl[off] = b;
}

// ---------------------------------------------------------------------------
// c2k: c2 = W2 @ b1. One wave per row.
// ---------------------------------------------------------------------------
__global__ __launch_bounds__(256)
void c2k(const float* __restrict__ w2, const float* __restrict__ b1,
         float* __restrict__ c2){
  const int wid = threadIdx.x >> 6, lane = threadIdx.x & 63;
  const int row = blockIdx.x * 4 + wid;
  float s = 0.f;
  #pragma unroll
  for (int t = 0; t < 16; t++){
    int e = lane + 64 * t;
    s += w2[(size_t)row * DM + e] * b1[e];
  }
  #pragma unroll
  for (int o = 32; o > 0; o >>= 1) s += __shfl_xor(s, o, 64);
  if (lane == 0) c2[row] = s;
}

// ---------------------------------------------------------------------------
// betak: beta[r] = sum_f (Yh+Yl)[r,f] * c2[f]. One wave per row.
// ---------------------------------------------------------------------------
__global__ __launch_bounds__(256)
void betak(const ushort* __restrict__ yh, const ushort* __restrict__ yl,
           const float* __restrict__ c2, float* __restrict__ beta){
  const int wid = threadIdx.x >> 6, lane = threadIdx.x & 63;
  const size_t r = (size_t)blockIdx.x * 4 + wid;
  const size_t base = r * DM + lane * 16;
  float s = 0.f;
  #pragma unroll
  for (int q = 0; q < 2; q++){
    bf16x8 h = *(const bf16x8*)&yh[base + q * 8];
    bf16x8 l = *(const bf16x8*)&yl[base + q * 8];
    float4 c0 = *(const float4*)&c2[lane * 16 + q * 8];
    float4 c1 = *(const float4*)&c2[lane * 16 + q * 8 + 4];
    s += (bf2f((ushort)h[0]) + bf2f((ushort)l[0])) * c0.x;
    s += (bf2f((ushort)h[1]) + bf2f((ushort)l[1])) * c0.y;
    s += (bf2f((ushort)h[2]) + bf2f((ushort)l[2])) * c0.z;
    s += (bf2f((ushort)h[3]) + bf2f((ushort)l[3])) * c0.w;
    s += (bf2f((ushort)h[4]) + bf2f((ushort)l[4])) * c1.x;
    s += (bf2f((ushort)h[5]) + bf2f((ushort)l[5])) * c1.y;
    s += (bf2f((ushort)h[6]) + bf2f((ushort)l[6])) * c1.z;
    s += (bf2f((ushort)h[7]) + bf2f((ushort)l[7])) * c1.w;
  }
  #pragma unroll
  for (int o = 32; o > 0; o >>= 1) s += __shfl_xor(s, o, 64);
  if (lane == 0) beta[r] = s;
}

// ---------------------------------------------------------------------------
// Shared split-bf16 B^T main loop: acc += A(m0..+128) @ B(n0..+128)^T over
// K=1024, all 4 planes async-staged (one plane per wave, 8 insts each).
// ---------------------------------------------------------------------------
__device__ __forceinline__ void bt_mainloop(
    const ushort* __restrict__ Aph, const ushort* __restrict__ Apl,
    const ushort* __restrict__ Bph, const ushort* __restrict__ Bpl,
    int m0, int n0, f32x4 (&acc)[4][4]){
  __shared__ alignas(16) ushort Ah[128*32];
  __shared__ alignas(16) ushort Al[128*32];
  __shared__ alignas(16) ushort Bh[128*32];
  __shared__ alignas(16) ushort Bl[128*32];

  const int tid = threadIdx.x;
  const int lane = tid & 63, wid = tid >> 6;
  const int wm = (wid & 1) * 64, wn = (wid >> 1) * 64;
  const int lr = lane & 15, lk = (lane >> 4) * 8;

  const ushort* plane = (wid == 0) ? Aph : (wid == 1) ? Apl : (wid == 2) ? Bph : Bpl;
  ushort* lds = (wid == 0) ? Ah : (wid == 1) ? Al : (wid == 2) ? Bh : Bl;
  const int r0 = (wid < 2) ? m0 : n0;
  const size_t goff = (size_t)(r0 + (lane >> 2)) * DM + (lane & 3) * 8;

  for (int k0 = 0; k0 < DM; k0 += 32){
    __syncthreads();
    const ushort* gp = plane + goff + k0;
    #pragma unroll
    for (int t = 0; t < 8; t++){
      GLOAD_LDS16(gp + (size_t)t * 16 * DM, lds + t * 512);
    }
    __syncthreads();

    bf16x8 fah[4], fal[4], fbh[4], fbl[4];
    #pragma unroll
    for (int i = 0; i < 4; i++){
      fah[i] = *(const bf16x8*)&Ah[(wm + i*16 + lr)*32 + lk];
      fal[i] = *(const bf16x8*)&Al[(wm + i*16 + lr)*32 + lk];
      fbh[i] = *(const bf16x8*)&Bh[(wn + i*16 + lr)*32 + lk];
      fbl[i] = *(const bf16x8*)&Bl[(wn + i*16 + lr)*32 + lk];
    }
    #pragma unroll
    for (int i = 0; i < 4; i++)
      #pragma unroll
      for (int j = 0; j < 4; j++){
        acc[i][j] = __builtin_amdgcn_mfma_f32_16x16x32_bf16(fah[i], fbh[j], acc[i][j], 0, 0, 0);
        acc[i][j] = __builtin_amdgcn_mfma_f32_16x16x32_bf16(fah[i], fbl[j], acc[i][j], 0, 0, 0);
        acc[i][j] = __builtin_amdgcn_mfma_f32_16x16x32_bf16(fal[i], fbh[j], acc[i][j], 0, 0, 0);
      }
  }
}

// gemm_bt_split: out planes = split(A @ B^T). Used for Gt (8x8) and Z (8x128).
__global__ __launch_bounds__(256, 2)
void gemm_bt_split(const ushort* __restrict__ Aph, const ushort* __restrict__ Apl,
                   const ushort* __restrict__ Bph, const ushort* __restrict__ Bpl,
                   ushort* __restrict__ oh, ushort* __restrict__ ol){
  const int m0 = blockIdx.y * 128, n0 = blockIdx.x * 128;
  f32x4 acc[4][4];
  for (int i = 0; i < 4; i++) for (int j = 0; j < 4; j++) acc[i][j] = (f32x4){0.f,0.f,0.f,0.f};
  bt_mainloop(Aph, Apl, Bph, Bpl, m0, n0, acc);

  const int lane = threadIdx.x & 63, wid = threadIdx.x >> 6;
  const int wm = (wid & 1) * 64, wn = (wid >> 1) * 64;
  const int lr = lane & 15;
  const int rbase = (lane >> 4) * 4;
  #pragma unroll
  for (int i = 0; i < 4; i++)
    #pragma unroll
    for (int j = 0; j < 4; j++){
      int gc = n0 + wn + j*16 + lr;
      #pragma unroll
      for (int r = 0; r < 4; r++){
        int gr = m0 + wm + i*16 + rbase + r;
        float v = acc[i][j][r];
        ushort hb = f2bf(v);
        size_t o = (size_t)gr * DM + gc;
        oh[o] = hb;
        ol[o] = f2bf(v - bf2f(hb));
      }
    }
}

// gemm_bt_f32: out[b,q,k] = Z[b,q,:] . Y[b,k,:]  (raw logits, f32)
// grid (1024, BATCH). XCD-swizzled: each XCD's 64 resident blocks form an
// 8x8 (q,k) square (8 MB working set, L3-covered). NT stores keep Z/Y in L3.
__global__ __launch_bounds__(256, 2)
void gemm_bt_f32(const ushort* __restrict__ Aph, const ushort* __restrict__ Apl,
                 const ushort* __restrict__ Bph, const ushort* __restrict__ Bpl,
                 float* __restrict__ out){
  const int b = blockIdx.y;
  const int id = blockIdx.x;
  const int c = id & 7;              // XCD residue (dispatch round-robin)
  const int m = (id >> 3) & 63;      // 64 blocks per XCD per 512-group
  const int s = m >> 3, u = m & 7;
  const int g = id >> 9;             // 512-block group
  const int qt = 16*g + 8*(c & 1) + s;
  const int kt = 8*(c >> 1) + u;
  const int m0 = qt * 128, n0 = kt * 128;
  const size_t abase = (size_t)b * SEQ * DM;

  f32x4 acc[4][4];
  for (int i = 0; i < 4; i++) for (int j = 0; j < 4; j++) acc[i][j] = (f32x4){0.f,0.f,0.f,0.f};
  bt_mainloop(Aph + abase, Apl + abase, Bph + abase, Bpl + abase, m0, n0, acc);

  const int lane = threadIdx.x & 63, wid = threadIdx.x >> 6;
  const int wm = (wid & 1) * 64, wn = (wid >> 1) * 64;
  const int lr = lane & 15;
  const int rbase = (lane >> 4) * 4;
  #pragma unroll
  for (int i = 0; i < 4; i++)
    #pragma unroll
    for (int j = 0; j < 4; j++){
      int gc = n0 + wn + j*16 + lr;
      #pragma unroll
      for (int r = 0; r < 4; r++){
        int gr = m0 + wm + i*16 + rbase + r;
        __builtin_nontemporal_store(acc[i][j][r],
            &out[((size_t)b * SEQ + gr) * SEQ + gc]);
      }
    }
}

// ---------------------------------------------------------------------------
// gemm_z_manual (compact-ws fallback): Z = split(hidden @ Gt^T), A staged
// manually from f32 (split in VALU), B async. grid (8,128).
// ---------------------------------------------------------------------------
#define ASTR 40
__global__ __launch_bounds__(256, 2)
void gemm_z_manual(const float* __restrict__ hidden,
                   const ushort* __restrict__ gth, const ushort* __restrict__ gtl,
                   ushort* __restrict__ zh, ushort* __restrict__ zl){
  const int m0 = blockIdx.y * 128, n0 = blockIdx.x * 128;
  __shared__ alignas(16) ushort Ah[128*ASTR];
  __shared__ alignas(16) ushort Al[128*ASTR];
  __shared__ alignas(16) ushort Bh[128*32];
  __shared__ alignas(16) ushort Bl[128*32];

  const int tid = threadIdx.x;
  const int lane = tid & 63, wid = tid >> 6;
  const int wm = (wid & 1) * 64, wn = (wid >> 1) * 64;
  const int lr = lane & 15, lk = (lane >> 4) * 8;

  const ushort* bp = (wid < 2) ? gth : gtl;
  ushort* blds = (wid < 2) ? Bh : Bl;
  const int tb = (wid & 1) * 4;
  const size_t bgoff = (size_t)(n0 + (lane >> 2)) * DM + (lane & 3) * 8;

  f32x4 acc[4][4];
  for (int i = 0; i < 4; i++) for (int j = 0; j < 4; j++) acc[i][j] = (f32x4){0.f,0.f,0.f,0.f};

  for (int k0 = 0; k0 < DM; k0 += 32){
    __syncthreads();
    const ushort* gb = bp + bgoff + k0;
    #pragma unroll
    for (int t = 0; t < 4; t++){
      GLOAD_LDS16(gb + (size_t)(tb + t) * 16 * DM, blds + (tb + t) * 512);
    }
    #pragma unroll
    for (int c = 0; c < 4; c++){
      int idx = c * 256 + tid;
      int row = idx >> 3, kq = (idx & 7) * 4;
      size_t ga = (size_t)(m0 + row) * DM + k0 + kq;
      float4 v = *(const float4*)&hidden[ga];
      ushort4 h4, l4;
      split4(v, h4, l4);
      *(ushort4*)&Ah[row*ASTR + kq] = h4;
      *(ushort4*)&Al[row*ASTR + kq] = l4;
    }
    __syncthreads();

    bf16x8 fah[4], fal[4], fbh[4], fbl[4];
    #pragma unroll
    for (int i = 0; i < 4; i++){
      fah[i] = *(const bf16x8*)&Ah[(wm + i*16 + lr)*ASTR + lk];
      fal[i] = *(const bf16x8*)&Al[(wm + i*16 + lr)*ASTR + lk];
      fbh[i] = *(const bf16x8*)&Bh[(wn + i*16 + lr)*32 + lk];
      fbl[i] = *(const bf16x8*)&Bl[(wn + i*16 + lr)*32 + lk];
    }
    #pragma unroll
    for (int i = 0; i < 4; i++)
      #pragma unroll
      for (int j = 0; j < 4; j++){
        acc[i][j] = __builtin_amdgcn_mfma_f32_16x16x32_bf16(fah[i], fbh[j], acc[i][j], 0, 0, 0);
        acc[i][j] = __builtin_amdgcn_mfma_f32_16x16x32_bf16(fah[i], fbl[j], acc[i][j], 0, 0, 0);
        acc[i][j] = __builtin_amdgcn_mfma_f32_16x16x32_bf16(fal[i], fbh[j], acc[i][j], 0, 0, 0);
      }
  }

  const int rbase = (lane >> 4) * 4;
  #pragma unroll
  for (int i = 0; i < 4; i++)
    #pragma unroll
    for (int j = 0; j < 4; j++){
      int gc = n0 + wn + j*16 + lr;
      #pragma unroll
      for (int r = 0; r < 4; r++){
        int gr = m0 + wm + i*16 + rbase + r;
        float v = acc[i][j][r];
        ushort hb = f2bf(v);
        size_t o = (size_t)gr * DM + gc;
        zh[o] = hb;
        zl[o] = f2bf(v - bf2f(hb));
      }
    }
}

// ---------------------------------------------------------------------------
// softmax_rows: in-place row softmax over last dim (4096), + beta[k] column
// bias pre-add. Non-temporal in/out via native ext-vector f32x4.
// ---------------------------------------------------------------------------
__global__ __launch_bounds__(256)
void softmax_rows(float* __restrict__ out, const float* __restrict__ beta){
  __shared__ float red[8];
  const size_t row = blockIdx.x;
  float* p = out + row * (size_t)SEQ;
  const float* bp = beta + ((row >> 12) << 12);
  const int tid = threadIdx.x, lane = tid & 63, wid = tid >> 6;

  f32x4 v[4];
  float m = -3.0e38f;
  #pragma unroll
  for (int c = 0; c < 4; c++){
    v[c] = __builtin_nontemporal_load(((const f32x4*)p) + c*256 + tid);
    f32x4 bb = *(((const f32x4*)bp) + c*256 + tid);
    v[c] += bb;
    m = fmaxf(m, fmaxf(fmaxf(v[c].x, v[c].y), fmaxf(v[c].z, v[c].w)));
  }
  #pragma unroll
  for (int o = 32; o > 0; o >>= 1) m = fmaxf(m, __shfl_xor(m, o, 64));
  if (lane == 0) red[wid] = m;
  __syncthreads();
  const float M = fmaxf(fmaxf(red[0], red[1]), fmaxf(red[2], red[3]));

  float s = 0.f;
  #pragma unroll
  for (int c = 0; c < 4; c++){
    v[c].x = __expf(v[c].x - M); s += v[c].x;
    v[c].y = __expf(v[c].y - M); s += v[c].y;
    v[c].z = __expf(v[c].z - M); s += v[c].z;
    v[c].w = __expf(v[c].w - M); s += v[c].w;
  }
  #pragma unroll
  for (int o = 32; o > 0; o >>= 1) s += __shfl_xor(s, o, 64);
  if (lane == 0) red[4 + wid] = s;
  __syncthreads();
  const float inv = 1.0f / (red[4] + red[5] + red[6] + red[7]);
  #pragma unroll
  for (int c = 0; c < 4; c++){
    v[c] *= inv;
    __builtin_nontemporal_store(v[c], ((f32x4*)p) + c*256 + tid);
  }
}

// ---------------------------------------------------------------------------
extern "C" void kernel_launch(void* const* d_in, const int* in_sizes, int n_in,
                              void* d_out, int out_size, void* d_ws, size_t ws_size,
                              hipStream_t stream){
  const float* hidden = (const float*)d_in[0];
  const float* pre    = (const float*)d_in[1];
  const float* w1     = (const float*)d_in[2];
  const float* b1     = (const float*)d_in[3];
  const float* w2     = (const float*)d_in[4];
  // b2 unused: its contribution is constant per softmax row and cancels.
  float* out = (float*)d_out;

  char* ws = (char*)d_ws;
  const size_t WP = (size_t)DM * DM * sizeof(ushort);     // 2 MiB
  const size_t AP = (size_t)MTOT * DM * sizeof(ushort);   // 32 MiB
  const bool big = ws_size >= 6*AP + 6*WP + (1u << 20);

  ushort *w1h, *w1l, *w2h, *w2l, *Gth, *Gtl, *Xh, *Xl, *Yh, *Yl, *Zh, *Zl;
  float *c2, *beta;
  if (big){
    Xh  = (ushort*)(ws + 0*AP);  Xl  = (ushort*)(ws + 1*AP);
    Yh  = (ushort*)(ws + 2*AP);  Yl  = (ushort*)(ws + 3*AP);
    Zh  = (ushort*)(ws + 4*AP);  Zl  = (ushort*)(ws + 5*AP);
    w1h = (ushort*)(ws + 6*AP);          w1l = (ushort*)(ws + 6*AP + WP);
    w2h = (ushort*)(ws + 6*AP + 2*WP);   w2l = (ushort*)(ws + 6*AP + 3*WP);
    Gth = (ushort*)(ws + 6*AP + 4*WP);   Gtl = (ushort*)(ws + 6*AP + 5*WP);
    c2   = (float*)(ws + 6*AP + 6*WP);
    beta = c2 + DM;
  } else {
    Zh  = (ushort*)(ws + 0*AP);  Zl  = (ushort*)(ws + 1*AP);
    Yh  = (ushort*)(ws + 2*AP);  Yl  = (ushort*)(ws + 3*AP);
    Gth = (ushort*)(ws + 4*AP);  Gtl = (ushort*)(ws + 4*AP + WP);
    w1h = (ushort*)(ws + 0);       w1l = (ushort*)(ws + WP);
    w2h = (ushort*)(ws + 2*WP);    w2l = (ushort*)(ws + 3*WP);
    c2   = (float*)(ws + 4*AP + 2*WP);
    beta = c2 + DM;
    Xh = Xl = nullptr;
  }

  prep_w_split<<<dim3(1024, 2), 256, 0, stream>>>(w1, w2, w1h, w1l, w2h, w2l);
  prep_xy<<<dim3(16384), 256, 0, stream>>>(hidden, pre, Xh, Xl, Yh, Yl, big ? 1 : 0);
  c2k<<<dim3(256), 256, 0, stream>>>(w2, b1, c2);
  // Gt = W2 @ W1^T  (so Z = X @ Gt^T = X @ W1 @ W2^T)
  gemm_bt_split<<<dim3(8, 8), 256, 0, stream>>>(w2h, w2l, w1h, w1l, Gth, Gtl);
  if (big){
    gemm_bt_split<<<dim3(8, 128), 256, 0, stream>>>(Xh, Xl, Gth, Gtl, Zh, Zl);
  } else {
    gemm_z_manual<<<dim3(8, 128), 256, 0, stream>>>(hidden, Gth, Gtl, Zh, Zl);
  }
  betak<<<dim3(4096), 256, 0, stream>>>(Yh, Yl, c2, beta);
  gemm_bt_f32<<<dim3(1024, BATCH), 256, 0, stream>>>(Zh, Zl, Yh, Yl, out);
  softmax_rows<<<dim3(MTOT), 256, 0, stream>>>(out, beta);
}